// Round 22
// baseline (103.168 us; speedup 1.0000x reference)
//
#include <hip/hip_runtime.h>
#include <hip/hip_bf16.h>

// Problem: T=2048, B=32, H=512
//   scores[b,t] = sum_o v[o] * tanh( hb[b,o] + sum_h enc[t,b,h] * W2[o,h] )
//   out[b,0,t]  = softmax_t(scores[b,:])
//
// R22: producer/consumer wave specialization (the one untried family; guide's
// m-series endpoint for exactly this barrier-coupled stall).
//  - 512 thr: waves 0-3 CONSUMERS (R16 COMPUTE, 64x64 tiles, acc[4][4]);
//    waves 4-7 PRODUCERS (R16 A_LOAD/cvt/A_WRITE + B_STAGE geometry, ping-pong,
//    counted vmcnt(12) within-wave only).
//  - 3-deep LDS ring (As[3]/Bs[3], 96KB, 1 block/CU). NO barriers in K-loop.
//  - Flags: pready[s] (4 producer adds), cdone[s] (4 consumer adds); producers
//    spin cdone[s-2] before reusing ring slot (s+1)%3.
// HARD-WON RULES: WRITE>>2MB = spill; gload_lds dest wave-uniform+lane*16B;
// lgkmcnt(0)+sched_barrier(0) before signaling (rule 18); R16 layouts verbatim.

#define TT 2048
#define BB 32
#define HH 512

typedef __attribute__((ext_vector_type(8))) short bf16x8;
typedef __attribute__((ext_vector_type(4))) float f32x4;

#define VMWAIT_(N) asm volatile("s_waitcnt vmcnt(" #N ")" ::: "memory")
#define VMWAIT(N) VMWAIT_(N)
#define LGKM0() asm volatile("s_waitcnt lgkmcnt(0)" ::: "memory")

static __device__ __forceinline__ unsigned cvt2(float a, float b) {
    union { __hip_bfloat162 h; unsigned u; } cv;
    cv.h = __float22bfloat162_rn(make_float2(a, b));   // v_cvt_pk_bf16_f32
    return cv.u;
}

static __device__ __forceinline__ unsigned short f2bf(float f) {
    unsigned int u = __float_as_uint(f);
    unsigned int r = (u + 0x7FFFu + ((u >> 16) & 1u)) >> 16;  // RNE
    return (unsigned short)r;
}

// tanh(x) = 1 - 2/(1+e^{2x});  inf-safe at both ends.
static __device__ __forceinline__ float fast_tanh(float x) {
    float e = __expf(2.0f * x);
    return 1.0f - 2.0f * __builtin_amdgcn_rcpf(1.0f + e);
}

static __device__ __forceinline__ void gload_lds16(const void* g, void* l) {
    __builtin_amdgcn_global_load_lds(
        (const __attribute__((address_space(1))) unsigned int*)g,
        (__attribute__((address_space(3))) unsigned int*)l, 16, 0, 0);
}

// ---- Kernel 1 (merged prep, = R16): blocks [0,1024) pack W2 swizzled image;
// blocks [1024,1088) compute hb.
// W2p: idx = nt*65536 + ks*8192 + j*64 + c; elem = W2[nt*128+j][ks*64+(c^((j&7)<<3))]
__global__ void prep_kernel(const float* __restrict__ W,
                            const float* __restrict__ hidden,
                            const float* __restrict__ b_attn,
                            short* __restrict__ W2p,
                            float* __restrict__ hb) {
    __shared__ float hrow[512];
    const int bid = blockIdx.x;
    if (bid < 1024) {
        int idx = bid * 256 + threadIdx.x;
        int nt = idx >> 16;
        int ks = (idx >> 13) & 7;
        int s  = idx & 8191;
        int j  = s >> 6;
        int c  = s & 63;
        int o  = nt * 128 + j;
        int k  = ks * 64 + (c ^ ((j & 7) << 3));
        W2p[idx] = (short)f2bf(W[o * 1024 + 512 + k]);
    } else {
        const int hbid = bid - 1024;
        int b = hbid >> 1;
        int o = ((hbid & 1) << 8) + threadIdx.x;
        for (int h = threadIdx.x; h < 512; h += 256) hrow[h] = hidden[b * 512 + h];
        __syncthreads();
        const float4* wr = reinterpret_cast<const float4*>(W + (size_t)o * 1024);
        const float4* hr = reinterpret_cast<const float4*>(hrow);
        float acc = b_attn[o];
#pragma unroll 8
        for (int i = 0; i < 128; ++i) {
            float4 w = wr[i], h4 = hr[i];
            acc += w.x * h4.x + w.y * h4.y + w.z * h4.z + w.w * h4.w;
        }
        hb[b * 512 + o] = acc;
    }
}

// ---- Kernel 2: 128x128 tile, K=512 in 8 steps of 64; producer/consumer waves.
// Grid 2048, XCD remap. M-rows contiguous r = t*32+b (R20-verified indexing).
__global__ __launch_bounds__(512, 1) void attn_main_kernel(
    const float* __restrict__ enc, const short* __restrict__ W2p,
    const float* __restrict__ hb, const float* __restrict__ v,
    float* __restrict__ scores_part)
{
    __shared__ short As[3][128 * 64];   // 48KB ring, swizzled c2 = c ^ ((r&7)<<3)
    __shared__ short Bs[3][128 * 64];   // 48KB ring, image pre-swizzled
    __shared__ float s_red[2][128];
    __shared__ int pready[8];
    __shared__ int cdone[8];

    const int tid = threadIdx.x;
    const int bid = blockIdx.x;
    const int w = (bid & 7) * 256 + (bid >> 3);  // bijective XCD remap
    const int nt = w & 3;
    const int mtile = w >> 2;
    const int r0 = mtile * 128;          // contiguous global row base

    const int wave = tid >> 6;
    const int lane = tid & 63;

    if (tid < 8) { pready[tid] = 0; cdone[tid] = 0; }
    __syncthreads();

    volatile int* vpready = pready;
    volatile int* vcdone = cdone;

    if (wave >= 4) {
        // ================= PRODUCER (waves 4..7, ptid 0..255) =================
        const int ptid = tid - 256;
        const int pwave = wave - 4;
        const int arow = ptid >> 3;          // 0..31
        const int afc = (ptid & 7) * 8;      // 0..56
        const float* encbase = enc + (size_t)(r0 + arow) * HH + afc;
        const short* bsrc = W2p + nt * 65536 + (pwave * 4) * 512 + lane * 8;

        float4 rA0[8], rA1[8];

#define P_A_LOAD(RA, KS)                                                            \
    {                                                                               \
        _Pragma("unroll")                                                           \
        for (int p = 0; p < 4; ++p) {                                               \
            const float* src = encbase + (size_t)p * 32 * HH + (KS) * 64;           \
            RA[p * 2]     = *reinterpret_cast<const float4*>(src);                  \
            RA[p * 2 + 1] = *reinterpret_cast<const float4*>(src + 4);              \
        }                                                                           \
    }

#define P_B_STAGE(KS, BUF)                                                          \
    {                                                                               \
        const short* s0 = bsrc + (KS) * 8192;                                       \
        _Pragma("unroll")                                                           \
        for (int c = 0; c < 4; ++c)                                                 \
            gload_lds16(s0 + c * 512, &Bs[BUF][(pwave * 4 + c) * 512]);             \
    }

#define P_A_WRITE(RA, BUF)                                                          \
    {                                                                               \
        _Pragma("unroll")                                                           \
        for (int p = 0; p < 4; ++p) {                                               \
            const int r = p * 32 + arow;                                            \
            uint4 pk;                                                               \
            pk.x = cvt2(RA[p * 2].x, RA[p * 2].y);                                  \
            pk.y = cvt2(RA[p * 2].z, RA[p * 2].w);                                  \
            pk.z = cvt2(RA[p * 2 + 1].x, RA[p * 2 + 1].y);                          \
            pk.w = cvt2(RA[p * 2 + 1].z, RA[p * 2 + 1].w);                          \
            const int cs = afc ^ ((r & 7) << 3);                                    \
            *reinterpret_cast<uint4*>(&As[BUF][r * 64 + cs]) = pk;                  \
        }                                                                           \
    }

#define P_SIGNAL(S)                                                                 \
    {                                                                               \
        LGKM0();                                                                    \
        __builtin_amdgcn_sched_barrier(0);                                          \
        if (lane == 0) atomicAdd(&pready[S], 1);                                    \
    }

        // prologue: loads for step 0
        P_A_LOAD(rA0, 0);
        P_B_STAGE(0, 0);

        // s = 0..6: load s+1, write s, signal s.
#pragma unroll
        for (int s = 0; s < 7; ++s) {
            const int nbuf = (s + 1) % 3;
            if (s >= 2) {   // ring slot nbuf reused from step s-2
                while (vcdone[s - 2] < 4) __builtin_amdgcn_s_sleep(2);
            }
            if (s & 1) { P_A_LOAD(rA0, s + 1); } else { P_A_LOAD(rA1, s + 1); }
            P_B_STAGE(s + 1, nbuf);
            if (s & 1) { P_A_WRITE(rA1, s % 3); } else { P_A_WRITE(rA0, s % 3); }
            VMWAIT(12);    // retire B_STAGE(s) (4 oldest); 12 newer stay in flight
            P_SIGNAL(s);
        }
        // s = 7: nothing to load; write and signal.
        P_A_WRITE(rA1, 7 % 3);
        VMWAIT(0);
        P_SIGNAL(7);

        // join epilogue barrier
        __syncthreads();
    } else {
        // ================= CONSUMER (waves 0..3) =================
        const int wr = wave >> 1;
        const int wc = wave & 1;
        const int lcol = lane & 15;
        const int lq = lane >> 4;

        f32x4 acc[4][4];
#pragma unroll
        for (int mt = 0; mt < 4; ++mt)
#pragma unroll
            for (int ns = 0; ns < 4; ++ns) acc[mt][ns] = (f32x4){0.f, 0.f, 0.f, 0.f};

#define C_COMPUTE(BUF)                                                              \
    {                                                                               \
        _Pragma("unroll")                                                           \
        for (int ksub = 0; ksub < 2; ++ksub) {                                      \
            const int kk = ksub * 32 + lq * 8;                                      \
            bf16x8 af[4], bfr[4];                                                   \
            _Pragma("unroll")                                                       \
            for (int mt = 0; mt < 4; ++mt) {                                        \
                const int r = wr * 64 + mt * 16 + lcol;                             \
                af[mt] = *reinterpret_cast<const bf16x8*>(                          \
                    &As[BUF][r * 64 + (kk ^ ((r & 7) << 3))]);                      \
            }                                                                       \
            _Pragma("unroll")                                                       \
            for (int ns = 0; ns < 4; ++ns) {                                        \
                const int j = wc * 64 + ns * 16 + lcol;                             \
                bfr[ns] = *reinterpret_cast<const bf16x8*>(                         \
                    &Bs[BUF][j * 64 + (kk ^ ((j & 7) << 3))]);                      \
            }                                                                       \
            _Pragma("unroll")                                                       \
            for (int mt = 0; mt < 4; ++mt)                                          \
                _Pragma("unroll")                                                   \
                for (int ns = 0; ns < 4; ++ns)                                      \
                    acc[mt][ns] = __builtin_amdgcn_mfma_f32_16x16x32_bf16(          \
                        af[mt], bfr[ns], acc[mt][ns], 0, 0, 0);                     \
        }                                                                           \
    }

#pragma unroll
        for (int s = 0; s < 8; ++s) {
            while (vpready[s] < 4) __builtin_amdgcn_s_sleep(2);
            C_COMPUTE(s % 3);
            LGKM0();                              // all ds_reads retired
            __builtin_amdgcn_sched_barrier(0);    // rule 18: pin the signal
            if (lane == 0) atomicAdd(&cdone[s], 1);
        }

        // ---- epilogue: tanh + v-dot; b = (local row)&31 (wr*64 ≡ 0 mod 32)
        float part[4][4];
#pragma unroll
        for (int mt = 0; mt < 4; ++mt)
#pragma unroll
            for (int j = 0; j < 4; ++j) part[mt][j] = 0.0f;

#pragma unroll
        for (int ns = 0; ns < 4; ++ns) {
            const int o = nt * 128 + wc * 64 + ns * 16 + lcol;
            const float vv = v[o];
            const float* hbcol = hb + o;
#pragma unroll
            for (int mt = 0; mt < 4; ++mt) {
                const int bbase = (mt * 16 + lq * 4) & 31;
#pragma unroll
                for (int j = 0; j < 4; ++j) {
                    const float hbv = hbcol[(bbase + j) * 512];
                    const float x = acc[mt][ns][j] + hbv;
                    part[mt][j] = fmaf(fast_tanh(x), vv, part[mt][j]);
                }
            }
        }

#pragma unroll
        for (int off = 1; off < 16; off <<= 1)
#pragma unroll
            for (int mt = 0; mt < 4; ++mt)
#pragma unroll
                for (int j = 0; j < 4; ++j)
                    part[mt][j] += __shfl_xor(part[mt][j], off, 64);

        if (lcol == 0) {
#pragma unroll
            for (int mt = 0; mt < 4; ++mt)
#pragma unroll
                for (int j = 0; j < 4; ++j)
                    s_red[wc][wr * 64 + mt * 16 + lq * 4 + j] = part[mt][j];
        }
        __syncthreads();
    }

    // scores_part in r-order: sp[nt*65536 + r]  (consumer threads tid<128)
    if (tid < 128)
        scores_part[(size_t)nt * (TT * BB) + r0 + tid] =
            s_red[0][tid] + s_red[1][tid];
}

// ---- Kernel 3: sum 4 N-tile partials + softmax over T per b (r-ordered sp).
__global__ void softmax_kernel(const float* __restrict__ sp, float* __restrict__ out) {
    __shared__ float wred[4];
    __shared__ float wsum[4];
    const int b = blockIdx.x;
    const int tid = threadIdx.x;   // 256
    float vals[8];
    float mx = -1e30f;
#pragma unroll
    for (int i = 0; i < 8; ++i) {
        const int t = i * 256 + tid;
        const size_t r = (size_t)t * BB + b;
        const float s = sp[r] + sp[(size_t)(TT * BB) + r] +
                        sp[(size_t)2 * (TT * BB) + r] + sp[(size_t)3 * (TT * BB) + r];
        vals[i] = s;
        mx = fmaxf(mx, s);
    }
#pragma unroll
    for (int off = 32; off; off >>= 1) mx = fmaxf(mx, __shfl_xor(mx, off, 64));
    if ((tid & 63) == 0) wred[tid >> 6] = mx;
    __syncthreads();
    mx = fmaxf(fmaxf(wred[0], wred[1]), fmaxf(wred[2], wred[3]));
    float s = 0.0f;
#pragma unroll
    for (int i = 0; i < 8; ++i) {
        vals[i] = __expf(vals[i] - mx);
        s += vals[i];
    }
#pragma unroll
    for (int off = 32; off; off >>= 1) s += __shfl_xor(s, off, 64);
    if ((tid & 63) == 0) wsum[tid >> 6] = s;
    __syncthreads();
    s = wsum[0] + wsum[1] + wsum[2] + wsum[3];
    const float inv = 1.0f / s;
#pragma unroll
    for (int i = 0; i < 8; ++i) out[b * TT + i * 256 + tid] = vals[i] * inv;
}

extern "C" void kernel_launch(void* const* d_in, const int* in_sizes, int n_in,
                              void* d_out, int out_size, void* d_ws, size_t ws_size,
                              hipStream_t stream) {
    const float* hidden = (const float*)d_in[0];   // (1,B,H)
    const float* enc    = (const float*)d_in[1];   // (T,B,H)
    const float* W      = (const float*)d_in[2];   // (H,2H)
    const float* b_attn = (const float*)d_in[3];   // (H,)
    const float* v      = (const float*)d_in[4];   // (H,)
    float* out = (float*)d_out;                    // (B,1,T)

    char* base = (char*)d_ws;
    short* W2p = (short*)base;                          // 524288 B
    float* hb  = (float*)(base + 524288);               // 65536 B
    float* sp  = (float*)(base + 589824);               // 4*65536*4 = 1048576 B

    prep_kernel<<<1088, 256, 0, stream>>>(W, hidden, b_attn, W2p, hb);
    attn_main_kernel<<<2048, 512, 0, stream>>>(enc, W2p, hb, v, sp);
    softmax_kernel<<<32, 256, 0, stream>>>(sp, out);
}

// Round 23
// 84.175 us; speedup vs baseline: 1.2256x; 1.2256x over previous
//
#include <hip/hip_runtime.h>
#include <hip/hip_bf16.h>

// Problem: T=2048, B=32, H=512
//   scores[b,t] = sum_o v[o] * tanh( hb[b,o] + sum_h enc[t,b,h] * W2[o,h] )
//   out[b,0,t]  = softmax_t(scores[b,:])
//
// R23: R16 structure with 128x256 tiles (2 N-tiles instead of 4): halves the
// duplicated A-staging work (the only lever class that ever won: reduce total
// staging). 512 thr / 8 waves (wr x wc = 2 x 4); per-wave code identical to
// R16 (64x64 tile, acc[4][4], same COMPUTE/swizzles). LDS 98KB -> 1 block/CU
// = 8 waves/CU (same waves/SIMD as R16). A-staging geometry = R13-verified
// (arow=tid>>2, afc=(tid&3)*16, 4 float4 -> 2 swizzled uint4).
//
// HARD-WON RULES (R2..R22): WRITE>>2MB on MAIN = spill; gload_lds dest
// wave-uniform+lane*16B (per-wave distinct); occupancy/scheduling/producer-
// consumer all null-to-negative at this shape; only staging-work reduction wins.

#define TT 2048
#define BB 32
#define HH 512

typedef __attribute__((ext_vector_type(8))) short bf16x8;
typedef __attribute__((ext_vector_type(4))) float f32x4;

static __device__ __forceinline__ unsigned cvt2(float a, float b) {
    union { __hip_bfloat162 h; unsigned u; } cv;
    cv.h = __float22bfloat162_rn(make_float2(a, b));   // v_cvt_pk_bf16_f32
    return cv.u;
}

static __device__ __forceinline__ unsigned short f2bf(float f) {
    unsigned int u = __float_as_uint(f);
    unsigned int r = (u + 0x7FFFu + ((u >> 16) & 1u)) >> 16;  // RNE
    return (unsigned short)r;
}

// tanh(x) = 1 - 2/(1+e^{2x});  inf-safe at both ends.
static __device__ __forceinline__ float fast_tanh(float x) {
    float e = __expf(2.0f * x);
    return 1.0f - 2.0f * __builtin_amdgcn_rcpf(1.0f + e);
}

static __device__ __forceinline__ void gload_lds16(const void* g, void* l) {
    __builtin_amdgcn_global_load_lds(
        (const __attribute__((address_space(1))) unsigned int*)g,
        (__attribute__((address_space(3))) unsigned int*)l, 16, 0, 0);
}

// ---- Kernel 1 (merged prep, = R16): blocks [0,1024) pack W2 swizzled image;
// blocks [1024,1088) compute hb.
// W2p: idx = p*65536 + ks*8192 + j*64 + c; elem = W2[p*128+j][ks*64+(c^((j&7)<<3))]
__global__ void prep_kernel(const float* __restrict__ W,
                            const float* __restrict__ hidden,
                            const float* __restrict__ b_attn,
                            short* __restrict__ W2p,
                            float* __restrict__ hb) {
    __shared__ float hrow[512];
    const int bid = blockIdx.x;
    if (bid < 1024) {
        int idx = bid * 256 + threadIdx.x;      // 262144 total
        int p  = idx >> 16;
        int ks = (idx >> 13) & 7;
        int s  = idx & 8191;
        int j  = s >> 6;
        int c  = s & 63;
        int o  = p * 128 + j;
        int k  = ks * 64 + (c ^ ((j & 7) << 3));
        W2p[idx] = (short)f2bf(W[o * 1024 + 512 + k]);
    } else {
        const int hbid = bid - 1024;
        int b = hbid >> 1;
        int o = ((hbid & 1) << 8) + threadIdx.x;
        for (int h = threadIdx.x; h < 512; h += 256) hrow[h] = hidden[b * 512 + h];
        __syncthreads();
        const float4* wr = reinterpret_cast<const float4*>(W + (size_t)o * 1024);
        const float4* hr = reinterpret_cast<const float4*>(hrow);
        float acc = b_attn[o];
#pragma unroll 8
        for (int i = 0; i < 128; ++i) {
            float4 w = wr[i], h4 = hr[i];
            acc += w.x * h4.x + w.y * h4.y + w.z * h4.z + w.w * h4.w;
        }
        hb[b * 512 + o] = acc;
    }
}

// ---- Kernel 2: 128x256-tile double-buffered GEMM + fused tanh/v-dot epilogue.
// Grid 1024, XCD remap w=(bid&7)*128+(bid>>3); nt=w&1 (256 cols), mtile=w>>1.
// M-rows contiguous r = t*32+b, r0 = mtile*128 (R20-verified indexing).
// 512 threads = 8 waves (wr 0..1 x wc 0..3), each wave 64x64, acc[4][4].
// K = 512 in 8 steps of 64. A: dist-2 reg ping-pong (4 float4/thread) ->
// cvt -> swizzled ds_write. B: gload_lds from pre-swizzled W2p (panels
// 2nt, 2nt+1), per-wave chunks. One barrier per step.
__global__ __launch_bounds__(512, 1) void attn_main_kernel(
    const float* __restrict__ enc, const short* __restrict__ W2p,
    const float* __restrict__ hb, const float* __restrict__ v,
    float* __restrict__ scores_part)
{
    __shared__ short As[2][128 * 64];   // 16KB x2, swizzled c2 = c ^ ((r&7)<<3)
    __shared__ short Bs[2][256 * 64];   // 32KB x2, image pre-swizzled (j = col 0..255)
    __shared__ float s_red[4][128];

    const int tid = threadIdx.x;
    const int bid = blockIdx.x;
    const int w = (bid & 7) * 128 + (bid >> 3);  // bijective (1024 % 8 == 0)
    const int nt = w & 1;                // N-tile (256 o-cols)
    const int mtile = w >> 1;            // 512 M-tiles
    const int r0 = mtile * 128;          // contiguous global row base (r = t*32+b)

    const int wave = tid >> 6;
    const int lane = tid & 63;
    const int wr = wave >> 2;            // 0..1 : row half (64 rows)
    const int wc = wave & 3;             // 0..3 : col quarter (64 of 256 cols)
    const int lcol = lane & 15;
    const int lq = lane >> 4;

    // A staging (R13-verified geometry): row = tid>>2, float cols (tid&3)*16..+15
    const int arow = tid >> 2;           // 0..127
    const int afc = (tid & 3) * 16;      // 0,16,32,48
    const float* encbase = enc + (size_t)(r0 + arow) * HH + afc;
    // B staging: wave stages chunks wave*4..+4 (of 32 1KB chunks per step).
    // Chunk c: panel p = 2nt + (c>>4), rows j0=(c&15)*8..+8.
    const short* bpan = W2p + (size_t)(2 * nt) * 65536 + lane * 8;

    f32x4 acc[4][4];
#pragma unroll
    for (int mt = 0; mt < 4; ++mt)
#pragma unroll
        for (int ns = 0; ns < 4; ++ns) acc[mt][ns] = (f32x4){0.f, 0.f, 0.f, 0.f};

    float4 rA0[4], rA1[4];

#define A_LOAD(RA, KS)                                                              \
    {                                                                               \
        const float* src = encbase + (KS) * 64;                                     \
        RA[0] = *reinterpret_cast<const float4*>(src);                              \
        RA[1] = *reinterpret_cast<const float4*>(src + 4);                          \
        RA[2] = *reinterpret_cast<const float4*>(src + 8);                          \
        RA[3] = *reinterpret_cast<const float4*>(src + 12);                         \
    }

#define B_STAGE(KS, BUF)                                                            \
    {                                                                               \
        _Pragma("unroll")                                                           \
        for (int cc = 0; cc < 4; ++cc) {                                            \
            const int c = wave * 4 + cc;                                            \
            const short* s0 = bpan + (size_t)(c >> 4) * 65536 + (KS) * 8192 +       \
                              (c & 15) * 512;                                       \
            gload_lds16(s0, &Bs[BUF][c * 512]);                                     \
        }                                                                           \
    }

#define A_WRITE(RA, BUF)                                                            \
    {                                                                               \
        uint4 q0, q1;                                                               \
        q0.x = cvt2(RA[0].x, RA[0].y);  q0.y = cvt2(RA[0].z, RA[0].w);              \
        q0.z = cvt2(RA[1].x, RA[1].y);  q0.w = cvt2(RA[1].z, RA[1].w);              \
        q1.x = cvt2(RA[2].x, RA[2].y);  q1.y = cvt2(RA[2].z, RA[2].w);              \
        q1.z = cvt2(RA[3].x, RA[3].y);  q1.w = cvt2(RA[3].z, RA[3].w);              \
        const int sw = (arow & 7) << 3;                                             \
        *reinterpret_cast<uint4*>(&As[BUF][arow * 64 + (afc ^ sw)]) = q0;           \
        *reinterpret_cast<uint4*>(&As[BUF][arow * 64 + ((afc + 8) ^ sw)]) = q1;     \
    }

#define COMPUTE(BUF)                                                                \
    {                                                                               \
        _Pragma("unroll")                                                           \
        for (int ksub = 0; ksub < 2; ++ksub) {                                      \
            const int kk = ksub * 32 + lq * 8;                                      \
            bf16x8 af[4], bfr[4];                                                   \
            _Pragma("unroll")                                                       \
            for (int mt = 0; mt < 4; ++mt) {                                        \
                const int r = wr * 64 + mt * 16 + lcol;                             \
                af[mt] = *reinterpret_cast<const bf16x8*>(                          \
                    &As[BUF][r * 64 + (kk ^ ((r & 7) << 3))]);                      \
            }                                                                       \
            _Pragma("unroll")                                                       \
            for (int ns = 0; ns < 4; ++ns) {                                        \
                const int j = wc * 64 + ns * 16 + lcol;                             \
                bfr[ns] = *reinterpret_cast<const bf16x8*>(                         \
                    &Bs[BUF][j * 64 + (kk ^ ((j & 7) << 3))]);                      \
            }                                                                       \
            _Pragma("unroll")                                                       \
            for (int mt = 0; mt < 4; ++mt)                                          \
                _Pragma("unroll")                                                   \
                for (int ns = 0; ns < 4; ++ns)                                      \
                    acc[mt][ns] = __builtin_amdgcn_mfma_f32_16x16x32_bf16(          \
                        af[mt], bfr[ns], acc[mt][ns], 0, 0, 0);                     \
        }                                                                           \
    }

    // ---- prologue: stage step 0; preload step 1 into rA1
    A_LOAD(rA0, 0);
    A_LOAD(rA1, 1);
    B_STAGE(0, 0);
    A_WRITE(rA0, 0);
    __syncthreads();

    // ---- main K-loop: 8 steps, hand-unrolled x2, static ping-pong.
#pragma unroll
    for (int s2 = 0; s2 < 4; ++s2) {
        const int s = s2 * 2;
        if (s + 2 < 8) A_LOAD(rA0, s + 2);
        B_STAGE(s + 1, 1);
        COMPUTE(0);
        A_WRITE(rA1, 1);
        __syncthreads();
        if (s + 3 < 8) A_LOAD(rA1, s + 3);
        if (s + 2 < 8) B_STAGE(s + 2, 0);
        COMPUTE(1);
        if (s + 2 < 8) {
            A_WRITE(rA0, 0);
            __syncthreads();
        }
    }

    // ---- epilogue: tanh + v-dot; b = (local row)&31 per row (wr*64 ≡ 0 mod 32)
    float part[4][4];
#pragma unroll
    for (int mt = 0; mt < 4; ++mt)
#pragma unroll
        for (int j = 0; j < 4; ++j) part[mt][j] = 0.0f;

#pragma unroll
    for (int ns = 0; ns < 4; ++ns) {
        const int o = nt * 256 + wc * 64 + ns * 16 + lcol;
        const float vv = v[o];
        const float* hbcol = hb + o;
#pragma unroll
        for (int mt = 0; mt < 4; ++mt) {
            const int bbase = (mt * 16 + lq * 4) & 31;
#pragma unroll
            for (int j = 0; j < 4; ++j) {
                const float hbv = hbcol[(bbase + j) * 512];
                const float x = acc[mt][ns][j] + hbv;
                part[mt][j] = fmaf(fast_tanh(x), vv, part[mt][j]);
            }
        }
    }

#pragma unroll
    for (int off = 1; off < 16; off <<= 1)
#pragma unroll
        for (int mt = 0; mt < 4; ++mt)
#pragma unroll
            for (int j = 0; j < 4; ++j)
                part[mt][j] += __shfl_xor(part[mt][j], off, 64);

    if (lcol == 0) {
#pragma unroll
        for (int mt = 0; mt < 4; ++mt)
#pragma unroll
            for (int j = 0; j < 4; ++j)
                s_red[wc][wr * 64 + mt * 16 + lq * 4 + j] = part[mt][j];
    }
    __syncthreads();

    // scores_part in r-order: sp[nt*65536 + r]
    if (tid < 128)
        scores_part[(size_t)nt * (TT * BB) + r0 + tid] =
            s_red[0][tid] + s_red[1][tid] + s_red[2][tid] + s_red[3][tid];
}

// ---- Kernel 3: sum 2 N-tile partials + softmax over T per b (r-ordered sp).
__global__ void softmax_kernel(const float* __restrict__ sp, float* __restrict__ out) {
    __shared__ float wred[4];
    __shared__ float wsum[4];
    const int b = blockIdx.x;
    const int tid = threadIdx.x;   // 256
    float vals[8];
    float mx = -1e30f;
#pragma unroll
    for (int i = 0; i < 8; ++i) {
        const int t = i * 256 + tid;
        const size_t r = (size_t)t * BB + b;
        const float s = sp[r] + sp[(size_t)(TT * BB) + r];
        vals[i] = s;
        mx = fmaxf(mx, s);
    }
#pragma unroll
    for (int off = 32; off; off >>= 1) mx = fmaxf(mx, __shfl_xor(mx, off, 64));
    if ((tid & 63) == 0) wred[tid >> 6] = mx;
    __syncthreads();
    mx = fmaxf(fmaxf(wred[0], wred[1]), fmaxf(wred[2], wred[3]));
    float s = 0.0f;
#pragma unroll
    for (int i = 0; i < 8; ++i) {
        vals[i] = __expf(vals[i] - mx);
        s += vals[i];
    }
#pragma unroll
    for (int off = 32; off; off >>= 1) s += __shfl_xor(s, off, 64);
    if ((tid & 63) == 0) wsum[tid >> 6] = s;
    __syncthreads();
    s = wsum[0] + wsum[1] + wsum[2] + wsum[3];
    const float inv = 1.0f / s;
#pragma unroll
    for (int i = 0; i < 8; ++i) out[b * TT + i * 256 + tid] = vals[i] * inv;
}

extern "C" void kernel_launch(void* const* d_in, const int* in_sizes, int n_in,
                              void* d_out, int out_size, void* d_ws, size_t ws_size,
                              hipStream_t stream) {
    const float* hidden = (const float*)d_in[0];   // (1,B,H)
    const float* enc    = (const float*)d_in[1];   // (T,B,H)
    const float* W      = (const float*)d_in[2];   // (H,2H)
    const float* b_attn = (const float*)d_in[3];   // (H,)
    const float* v      = (const float*)d_in[4];   // (H,)
    float* out = (float*)d_out;                    // (B,1,T)

    char* base = (char*)d_ws;
    short* W2p = (short*)base;                          // 524288 B
    float* hb  = (float*)(base + 524288);               // 65536 B
    float* sp  = (float*)(base + 589824);               // 2*65536*4 = 524288 B

    prep_kernel<<<1088, 256, 0, stream>>>(W, hidden, b_attn, W2p, hb);
    attn_main_kernel<<<1024, 512, 0, stream>>>(enc, W2p, hb, v, sp);
    softmax_kernel<<<32, 256, 0, stream>>>(sp, out);
}